// Round 8
// baseline (161.901 us; speedup 1.0000x reference)
//
#include <hip/hip_runtime.h>
#include <hip/hip_bf16.h>

using short8 = __attribute__((ext_vector_type(8))) short;
using f32x4  = __attribute__((ext_vector_type(4))) float;

#define MBATCH 16
#define NUMV   128
#define LEN    64
#define SZ     256

__device__ __forceinline__ unsigned short bfbits(float x) {
  union { float f; unsigned u; } c; c.f = x;
  return (unsigned short)((c.u + 0x8000u) >> 16);   // round-to-nearest
}

// ---------------- prep 1: u[bn][s], v[bn][s] (layer-1 factorization) ----------------
__global__ void uv_prep(const float* __restrict__ in_, const float* __restrict__ W1,
                        const float* __restrict__ b1,
                        float* __restrict__ u, float* __restrict__ v) {
  int bn = blockIdx.x;
  int n  = bn & (NUMV - 1);
  int s  = threadIdx.x;                // 256 threads
  __shared__ float xs[LEN];
  if (s < LEN) xs[s] = in_[bn * LEN + s];
  __syncthreads();
  float fn = (float)n;
  float uu = fn * W1[64 * SZ + s];
  float vv = fn * W1[129 * SZ + s] + b1[s];
  for (int c = 0; c < LEN; ++c) {
    uu = fmaf(xs[c], W1[c * SZ + s], uu);
    vv = fmaf(xs[c], W1[(65 + c) * SZ + s], vv);
  }
  u[bn * SZ + s] = uu;
  v[bn * SZ + s] = vv;
}

// ---------------- prep 2: W2/W3/W4 -> bf16 A-fragments, lane-coalesced ----------------
// frag f = ((L*4 + wv)*4 + m)*8 + kb ; 64 lanes x 16B contiguous per frag.
// lane (l16,q) of frag: Wt[ch = wv*64+m*16+l16][kb*32 + q*8 + 0..7] = W[k][ch]
__global__ void w_prep(const float* __restrict__ W2, const float* __restrict__ W3,
                       const float* __restrict__ W4, short* __restrict__ wlay) {
  int L = blockIdx.x >> 3, kb = blockIdx.x & 7;     // 24 blocks
  const float* W = (L == 0) ? W2 : (L == 1) ? W3 : W4;
  int m = threadIdx.x >> 6, lane = threadIdx.x & 63;
  int l16 = lane & 15, q = lane >> 4;
  for (int wv = 0; wv < 4; ++wv) {
    int ch = wv * 64 + m * 16 + l16;
    short8 pk;
    for (int i = 0; i < 8; ++i)
      pk[i] = (short)bfbits(W[(kb * 32 + q * 8 + i) * SZ + ch]);
    int f = ((L * 4 + wv) * 4 + m) * 8 + kb;
    reinterpret_cast<short8*>(wlay)[f * 64 + lane] = pk;
  }
}

// ---------------- main fused kernel ----------------
// One WG per (b, a, jhalf): 64 rows, 256 threads = 4 waves.
// Wave w: 64 out-channels (4 M-frags) x 64 rows (4 N-frags). A-operand lives in
// registers (4 x short8 per kb), software-pipelined 1 kb ahead from a lane-coalesced
// global layout (L2-resident). ZERO barriers inside the K-loop; hbuf read-only per layer.
// LDS = 32KB hbuf only.  launch_bounds(,3): cap unified regs ~170 -> 3 waves/SIMD
// (acc[4][4] = 64 AGPR counts against the unified file; at (,2) we sat at 172 total
//  = 2 waves/SIMD and the MFMA pipe idled 65% on weight-load latency).
__global__ __launch_bounds__(256, 3) void fused_mlp(
    const float* __restrict__ u, const float* __restrict__ v,
    const short* __restrict__ wlay,
    const float* __restrict__ b2, const float* __restrict__ b3, const float* __restrict__ b4,
    float* __restrict__ partial) {
  __shared__ __align__(16) short hbuf[64 * 256];   // 32 KB, byte ^= (row&7)<<4

  int wg = blockIdx.x;
  int b = wg >> 8, a = (wg >> 1) & 127, jh = wg & 1;
  int tid = threadIdx.x;
  int wave = tid >> 6, lane = tid & 63;
  int l16 = lane & 15, q = lane >> 4;

  const short8* wcl = reinterpret_cast<const short8*>(wlay) + lane;  // per-lane base

  short8 awA[4], awB[4];
  // preload layer-0 kb=0 fragments (latency hidden under h1 phase)
  #pragma unroll
  for (int m = 0; m < 4; ++m)
    awA[m] = wcl[(((0 * 4 + wave) * 4 + m) * 8 + 0) * 64];

  // ---- h1 = relu(u[b,j] + v[b,a]) -> bf16, swizzled row-major in LDS ----
  {
    const float4* ub = (const float4*)(u + (size_t)b * NUMV * SZ) + jh * 64 * 64;
    const float4* vb = (const float4*)(v + ((size_t)b * NUMV + a) * SZ);
    #pragma unroll
    for (int it = 0; it < 16; ++it) {
      int flat = tid + it * 256;          // over 64 rows * 64 col-quads
      int jr = flat >> 6, c4 = flat & 63;
      float4 uu = ub[jr * 64 + c4];
      float4 vv = vb[c4];
      unsigned lo = (unsigned)bfbits(fmaxf(uu.x + vv.x, 0.f))
                  | ((unsigned)bfbits(fmaxf(uu.y + vv.y, 0.f)) << 16);
      unsigned hi = (unsigned)bfbits(fmaxf(uu.z + vv.z, 0.f))
                  | ((unsigned)bfbits(fmaxf(uu.w + vv.w, 0.f)) << 16);
      int byte = (jr * 512 + c4 * 8) ^ ((jr & 7) << 4);
      uint2 pk; pk.x = lo; pk.y = hi;
      *reinterpret_cast<uint2*>((char*)hbuf + byte) = pk;
    }
  }

  __syncthreads();        // h1 visible to all waves

  #pragma unroll
  for (int L = 0; L < 3; ++L) {
    const float* bb = (L == 0) ? b2 : (L == 1) ? b3 : b4;

    f32x4 acc[4][4];
    #pragma unroll
    for (int m = 0; m < 4; ++m)
      #pragma unroll
      for (int n = 0; n < 4; ++n)
        acc[m][n] = f32x4{0.f, 0.f, 0.f, 0.f};

    #pragma unroll
    for (int kb = 0; kb < 8; ++kb) {
      // prefetch next A-fragments into the other register bank
      if (kb < 7) {
        if ((kb & 1) == 0) {
          #pragma unroll
          for (int m = 0; m < 4; ++m)
            awB[m] = wcl[(((L * 4 + wave) * 4 + m) * 8 + kb + 1) * 64];
        } else {
          #pragma unroll
          for (int m = 0; m < 4; ++m)
            awA[m] = wcl[(((L * 4 + wave) * 4 + m) * 8 + kb + 1) * 64];
        }
      } else if (L < 2) {
        #pragma unroll
        for (int m = 0; m < 4; ++m)
          awA[m] = wcl[((((L + 1) * 4 + wave) * 4 + m) * 8 + 0) * 64];
      }
      short8 bfr[4];
      #pragma unroll
      for (int n = 0; n < 4; ++n) {
        int row = n * 16 + l16;
        int byte = (row * 512 + kb * 64 + q * 16) ^ ((row & 7) << 4);
        bfr[n] = *reinterpret_cast<const short8*>((char*)hbuf + byte);
      }
      __builtin_amdgcn_s_setprio(1);
      if ((kb & 1) == 0) {
        #pragma unroll
        for (int m = 0; m < 4; ++m)
          #pragma unroll
          for (int n = 0; n < 4; ++n)
            acc[m][n] = __builtin_amdgcn_mfma_f32_16x16x32_bf16(awA[m], bfr[n], acc[m][n], 0, 0, 0);
      } else {
        #pragma unroll
        for (int m = 0; m < 4; ++m)
          #pragma unroll
          for (int n = 0; n < 4; ++n)
            acc[m][n] = __builtin_amdgcn_mfma_f32_16x16x32_bf16(awB[m], bfr[n], acc[m][n], 0, 0, 0);
      }
      __builtin_amdgcn_s_setprio(0);
    }

    __syncthreads();      // all waves done reading hbuf for this layer

    if (L < 2) {
      // epilogue: h_next[row][ch] = relu(acc+bias) -> swizzled hbuf, in place
      #pragma unroll
      for (int m = 0; m < 4; ++m) {
        f32x4 bv = *reinterpret_cast<const f32x4*>(bb + wave * 64 + m * 16 + q * 4);
        int ch = wave * 64 + m * 16 + q * 4;
        #pragma unroll
        for (int n = 0; n < 4; ++n) {
          int row = n * 16 + l16;
          f32x4 t = acc[m][n];
          unsigned lo = (unsigned)bfbits(fmaxf(t[0] + bv[0], 0.f))
                      | ((unsigned)bfbits(fmaxf(t[1] + bv[1], 0.f)) << 16);
          unsigned hi = (unsigned)bfbits(fmaxf(t[2] + bv[2], 0.f))
                      | ((unsigned)bfbits(fmaxf(t[3] + bv[3], 0.f)) << 16);
          int byte = (row * 512 + ch * 2) ^ ((row & 7) << 4);
          uint2 pk; pk.x = lo; pk.y = hi;
          *reinterpret_cast<uint2*>((char*)hbuf + byte) = pk;
        }
      }
      __syncthreads();    // h_next visible before next layer's reads
    } else {
      // final layer: relu+bias, sum this wave's 64 rows, write partial directly
      #pragma unroll
      for (int m = 0; m < 4; ++m) {
        f32x4 bv = *reinterpret_cast<const f32x4*>(bb + wave * 64 + m * 16 + q * 4);
        f32x4 s = f32x4{0.f, 0.f, 0.f, 0.f};
        #pragma unroll
        for (int n = 0; n < 4; ++n) {
          s[0] += fmaxf(acc[m][n][0] + bv[0], 0.f);
          s[1] += fmaxf(acc[m][n][1] + bv[1], 0.f);
          s[2] += fmaxf(acc[m][n][2] + bv[2], 0.f);
          s[3] += fmaxf(acc[m][n][3] + bv[3], 0.f);
        }
        #pragma unroll
        for (int r = 0; r < 4; ++r) {
          float x = s[r];
          x += __shfl_xor(x, 1);
          x += __shfl_xor(x, 2);
          x += __shfl_xor(x, 4);
          x += __shfl_xor(x, 8);
          s[r] = x;
        }
        if (l16 == 0) {
          float4 o; o.x = s[0]; o.y = s[1]; o.z = s[2]; o.w = s[3];
          *reinterpret_cast<float4*>(partial + (size_t)wg * SZ + wave * 64 + m * 16 + q * 4) = o;
        }
      }
    }
  }
}

// ---------------- final reduction over (a, jhalf): 256 slices per batch ----------------
__global__ void reduce_partials(const float* __restrict__ partial, float* __restrict__ out) {
  int b = blockIdx.x;            // 16 blocks x 256 threads
  int s = threadIdx.x;
  const float* p = partial + (size_t)b * 256 * SZ + s;
  float acc = 0.f;
  for (int i = 0; i < 256; ++i) acc += p[(size_t)i * SZ];
  out[b * SZ + s] = acc;
}

extern "C" void kernel_launch(void* const* d_in, const int* in_sizes, int n_in,
                              void* d_out, int out_size, void* d_ws, size_t ws_size,
                              hipStream_t stream) {
  const float* in_ = (const float*)d_in[0];
  const float* W1  = (const float*)d_in[1];
  const float* b1  = (const float*)d_in[2];
  const float* W2  = (const float*)d_in[3];
  const float* b2  = (const float*)d_in[4];
  const float* W3  = (const float*)d_in[5];
  const float* b3  = (const float*)d_in[6];
  const float* W4  = (const float*)d_in[7];
  const float* b4  = (const float*)d_in[8];
  float* out = (float*)d_out;

  char* ws = (char*)d_ws;
  float* u       = (float*)(ws);                                 // 2 MB
  float* v       = (float*)(ws + (2u << 20));                    // 2 MB
  short* wlay    = (short*)(ws + (4u << 20));                    // 384 KB
  float* partial = (float*)(ws + (4u << 20) + (1u << 19));       // 4 MB

  uv_prep<<<MBATCH * NUMV, 256, 0, stream>>>(in_, W1, b1, u, v);
  w_prep<<<24, 256, 0, stream>>>(W2, W3, W4, wlay);
  fused_mlp<<<MBATCH * NUMV * 2, 256, 0, stream>>>(u, v, wlay, b2, b3, b4, partial);
  reduce_partials<<<MBATCH, 256, 0, stream>>>(partial, out);
}

// Round 9
// 128.979 us; speedup vs baseline: 1.2552x; 1.2552x over previous
//
#include <hip/hip_runtime.h>
#include <hip/hip_bf16.h>

using short8 = __attribute__((ext_vector_type(8))) short;
using f32x4  = __attribute__((ext_vector_type(4))) float;

#define MBATCH 16
#define NUMV   128
#define LEN    64
#define SZ     256

__device__ __forceinline__ unsigned short bfbits(float x) {
  union { float f; unsigned u; } c; c.f = x;
  return (unsigned short)((c.u + 0x8000u) >> 16);   // round-to-nearest
}

// ---------------- prep 1: u[bn][s], v[bn][s] (layer-1 factorization) ----------------
__global__ void uv_prep(const float* __restrict__ in_, const float* __restrict__ W1,
                        const float* __restrict__ b1,
                        float* __restrict__ u, float* __restrict__ v) {
  int bn = blockIdx.x;
  int n  = bn & (NUMV - 1);
  int s  = threadIdx.x;                // 256 threads
  __shared__ float xs[LEN];
  if (s < LEN) xs[s] = in_[bn * LEN + s];
  __syncthreads();
  float fn = (float)n;
  float uu = fn * W1[64 * SZ + s];
  float vv = fn * W1[129 * SZ + s] + b1[s];
  for (int c = 0; c < LEN; ++c) {
    uu = fmaf(xs[c], W1[c * SZ + s], uu);
    vv = fmaf(xs[c], W1[(65 + c) * SZ + s], vv);
  }
  u[bn * SZ + s] = uu;
  v[bn * SZ + s] = vv;
}

// ---------------- prep 2: W2/W3/W4 -> bf16 A-fragments, lane-coalesced ----------------
// frag f = ((L*4 + wv)*4 + m)*8 + kb ; 64 lanes x 16B contiguous per frag.
// lane (l16,q) of frag: Wt[ch = wv*64+m*16+l16][kb*32 + q*8 + 0..7] = W[k][ch]
__global__ void w_prep(const float* __restrict__ W2, const float* __restrict__ W3,
                       const float* __restrict__ W4, short* __restrict__ wlay) {
  int L = blockIdx.x >> 3, kb = blockIdx.x & 7;     // 24 blocks
  const float* W = (L == 0) ? W2 : (L == 1) ? W3 : W4;
  int m = threadIdx.x >> 6, lane = threadIdx.x & 63;
  int l16 = lane & 15, q = lane >> 4;
  for (int wv = 0; wv < 4; ++wv) {
    int ch = wv * 64 + m * 16 + l16;
    short8 pk;
    for (int i = 0; i < 8; ++i)
      pk[i] = (short)bfbits(W[(kb * 32 + q * 8 + i) * SZ + ch]);
    int f = ((L * 4 + wv) * 4 + m) * 8 + kb;
    reinterpret_cast<short8*>(wlay)[f * 64 + lane] = pk;
  }
}

// ---------------- main fused kernel ----------------
// One WG per (b, a, jhalf): 64 rows, 256 threads = 4 waves.
// Wave w: 64 out-channels (4 M-frags) x 64 rows (4 N-frags). SINGLE weight register
// bank aw[4] (16 VGPR): loads for kb+1 issue after kb's MFMAs read aw (WAR), so the
// compiler staggers load[m] after the MFMAs using aw[m]. Exposed latency is covered
// by sibling waves: total demand ~156 regs -> 3 waves/SIMD at launch_bounds(,3).
// ZERO barriers inside the K-loop; LDS = 32KB hbuf only.
__global__ __launch_bounds__(256, 3) void fused_mlp(
    const float* __restrict__ u, const float* __restrict__ v,
    const short* __restrict__ wlay,
    const float* __restrict__ b2, const float* __restrict__ b3, const float* __restrict__ b4,
    float* __restrict__ partial) {
  __shared__ __align__(16) short hbuf[64 * 256];   // 32 KB, byte ^= (row&7)<<4

  int wg = blockIdx.x;
  int b = wg >> 8, a = (wg >> 1) & 127, jh = wg & 1;
  int tid = threadIdx.x;
  int wave = tid >> 6, lane = tid & 63;
  int l16 = lane & 15, q = lane >> 4;

  const short8* wcl = reinterpret_cast<const short8*>(wlay) + lane;  // per-lane base

  short8 aw[4];
  // preload layer-0 kb=0 fragments (latency hidden under h1 phase)
  #pragma unroll
  for (int m = 0; m < 4; ++m)
    aw[m] = wcl[(((0 * 4 + wave) * 4 + m) * 8 + 0) * 64];

  // ---- h1 = relu(u[b,j] + v[b,a]) -> bf16, swizzled row-major in LDS ----
  {
    const float4* ub = (const float4*)(u + (size_t)b * NUMV * SZ) + jh * 64 * 64;
    const float4* vb = (const float4*)(v + ((size_t)b * NUMV + a) * SZ);
    #pragma unroll
    for (int it = 0; it < 16; ++it) {
      int flat = tid + it * 256;          // over 64 rows * 64 col-quads
      int jr = flat >> 6, c4 = flat & 63;
      float4 uu = ub[jr * 64 + c4];
      float4 vv = vb[c4];
      unsigned lo = (unsigned)bfbits(fmaxf(uu.x + vv.x, 0.f))
                  | ((unsigned)bfbits(fmaxf(uu.y + vv.y, 0.f)) << 16);
      unsigned hi = (unsigned)bfbits(fmaxf(uu.z + vv.z, 0.f))
                  | ((unsigned)bfbits(fmaxf(uu.w + vv.w, 0.f)) << 16);
      int byte = (jr * 512 + c4 * 8) ^ ((jr & 7) << 4);
      uint2 pk; pk.x = lo; pk.y = hi;
      *reinterpret_cast<uint2*>((char*)hbuf + byte) = pk;
    }
  }

  __syncthreads();        // h1 visible to all waves

  #pragma unroll
  for (int L = 0; L < 3; ++L) {
    const float* bb = (L == 0) ? b2 : (L == 1) ? b3 : b4;

    f32x4 acc[4][4];
    #pragma unroll
    for (int m = 0; m < 4; ++m)
      #pragma unroll
      for (int n = 0; n < 4; ++n)
        acc[m][n] = f32x4{0.f, 0.f, 0.f, 0.f};

    #pragma unroll
    for (int kb = 0; kb < 8; ++kb) {
      short8 bfr[4];
      #pragma unroll
      for (int n = 0; n < 4; ++n) {
        int row = n * 16 + l16;
        int byte = (row * 512 + kb * 64 + q * 16) ^ ((row & 7) << 4);
        bfr[n] = *reinterpret_cast<const short8*>((char*)hbuf + byte);
      }
      __builtin_amdgcn_s_setprio(1);
      #pragma unroll
      for (int m = 0; m < 4; ++m)
        #pragma unroll
        for (int n = 0; n < 4; ++n)
          acc[m][n] = __builtin_amdgcn_mfma_f32_16x16x32_bf16(aw[m], bfr[n], acc[m][n], 0, 0, 0);
      __builtin_amdgcn_s_setprio(0);
      // reload aw for next kb (WAR on this step's MFMAs -> compiler staggers per-m)
      if (kb < 7) {
        #pragma unroll
        for (int m = 0; m < 4; ++m)
          aw[m] = wcl[(((L * 4 + wave) * 4 + m) * 8 + kb + 1) * 64];
      } else if (L < 2) {
        #pragma unroll
        for (int m = 0; m < 4; ++m)
          aw[m] = wcl[((((L + 1) * 4 + wave) * 4 + m) * 8 + 0) * 64];
      }
    }

    __syncthreads();      // all waves done reading hbuf for this layer

    if (L < 2) {
      // epilogue: h_next[row][ch] = relu(acc+bias) -> swizzled hbuf, in place
      #pragma unroll
      for (int m = 0; m < 4; ++m) {
        f32x4 bv = *reinterpret_cast<const f32x4*>(bb + wave * 64 + m * 16 + q * 4);
        int ch = wave * 64 + m * 16 + q * 4;
        #pragma unroll
        for (int n = 0; n < 4; ++n) {
          int row = n * 16 + l16;
          f32x4 t = acc[m][n];
          unsigned lo = (unsigned)bfbits(fmaxf(t[0] + bv[0], 0.f))
                      | ((unsigned)bfbits(fmaxf(t[1] + bv[1], 0.f)) << 16);
          unsigned hi = (unsigned)bfbits(fmaxf(t[2] + bv[2], 0.f))
                      | ((unsigned)bfbits(fmaxf(t[3] + bv[3], 0.f)) << 16);
          int byte = (row * 512 + ch * 2) ^ ((row & 7) << 4);
          uint2 pk; pk.x = lo; pk.y = hi;
          *reinterpret_cast<uint2*>((char*)hbuf + byte) = pk;
        }
      }
      __syncthreads();    // h_next visible before next layer's reads
    } else {
      // final layer: relu+bias, sum this wave's 64 rows, write partial directly
      #pragma unroll
      for (int m = 0; m < 4; ++m) {
        f32x4 bv = *reinterpret_cast<const f32x4*>(bb + wave * 64 + m * 16 + q * 4);
        f32x4 s = f32x4{0.f, 0.f, 0.f, 0.f};
        #pragma unroll
        for (int n = 0; n < 4; ++n) {
          s[0] += fmaxf(acc[m][n][0] + bv[0], 0.f);
          s[1] += fmaxf(acc[m][n][1] + bv[1], 0.f);
          s[2] += fmaxf(acc[m][n][2] + bv[2], 0.f);
          s[3] += fmaxf(acc[m][n][3] + bv[3], 0.f);
        }
        #pragma unroll
        for (int r = 0; r < 4; ++r) {
          float x = s[r];
          x += __shfl_xor(x, 1);
          x += __shfl_xor(x, 2);
          x += __shfl_xor(x, 4);
          x += __shfl_xor(x, 8);
          s[r] = x;
        }
        if (l16 == 0) {
          float4 o; o.x = s[0]; o.y = s[1]; o.z = s[2]; o.w = s[3];
          *reinterpret_cast<float4*>(partial + (size_t)wg * SZ + wave * 64 + m * 16 + q * 4) = o;
        }
      }
    }
  }
}

// ---------------- final reduction over (a, jhalf): 256 slices per batch ----------------
__global__ void reduce_partials(const float* __restrict__ partial, float* __restrict__ out) {
  int b = blockIdx.x;            // 16 blocks x 256 threads
  int s = threadIdx.x;
  const float* p = partial + (size_t)b * 256 * SZ + s;
  float acc = 0.f;
  for (int i = 0; i < 256; ++i) acc += p[(size_t)i * SZ];
  out[b * SZ + s] = acc;
}

extern "C" void kernel_launch(void* const* d_in, const int* in_sizes, int n_in,
                              void* d_out, int out_size, void* d_ws, size_t ws_size,
                              hipStream_t stream) {
  const float* in_ = (const float*)d_in[0];
  const float* W1  = (const float*)d_in[1];
  const float* b1  = (const float*)d_in[2];
  const float* W2  = (const float*)d_in[3];
  const float* b2  = (const float*)d_in[4];
  const float* W3  = (const float*)d_in[5];
  const float* b3  = (const float*)d_in[6];
  const float* W4  = (const float*)d_in[7];
  const float* b4  = (const float*)d_in[8];
  float* out = (float*)d_out;

  char* ws = (char*)d_ws;
  float* u       = (float*)(ws);                                 // 2 MB
  float* v       = (float*)(ws + (2u << 20));                    // 2 MB
  short* wlay    = (short*)(ws + (4u << 20));                    // 384 KB
  float* partial = (float*)(ws + (4u << 20) + (1u << 19));       // 4 MB

  uv_prep<<<MBATCH * NUMV, 256, 0, stream>>>(in_, W1, b1, u, v);
  w_prep<<<24, 256, 0, stream>>>(W2, W3, W4, wlay);
  fused_mlp<<<MBATCH * NUMV * 2, 256, 0, stream>>>(u, v, wlay, b2, b3, b4, partial);
  reduce_partials<<<MBATCH, 256, 0, stream>>>(partial, out);
}

// Round 10
// 126.146 us; speedup vs baseline: 1.2834x; 1.0225x over previous
//
#include <hip/hip_runtime.h>
#include <hip/hip_bf16.h>

using short8 = __attribute__((ext_vector_type(8))) short;
using f32x4  = __attribute__((ext_vector_type(4))) float;

#define MBATCH 16
#define NUMV   128
#define LEN    64
#define SZ     256

__device__ __forceinline__ unsigned short bfbits(float x) {
  union { float f; unsigned u; } c; c.f = x;
  return (unsigned short)((c.u + 0x8000u) >> 16);   // round-to-nearest
}

// ---------------- prep 1: u[bn][s], v[bn][s] (layer-1 factorization) ----------------
__global__ void uv_prep(const float* __restrict__ in_, const float* __restrict__ W1,
                        const float* __restrict__ b1,
                        float* __restrict__ u, float* __restrict__ v) {
  int bn = blockIdx.x;
  int n  = bn & (NUMV - 1);
  int s  = threadIdx.x;                // 256 threads
  __shared__ float xs[LEN];
  if (s < LEN) xs[s] = in_[bn * LEN + s];
  __syncthreads();
  float fn = (float)n;
  float uu = fn * W1[64 * SZ + s];
  float vv = fn * W1[129 * SZ + s] + b1[s];
  for (int c = 0; c < LEN; ++c) {
    uu = fmaf(xs[c], W1[c * SZ + s], uu);
    vv = fmaf(xs[c], W1[(65 + c) * SZ + s], vv);
  }
  u[bn * SZ + s] = uu;
  v[bn * SZ + s] = vv;
}

// ---------------- prep 2: W2/W3/W4 -> bf16 A-fragments ----------------
// Linear step-major layout: step s = L*8+kb is a 16KB chunk; within it wave wv's
// 4KB block holds m-frags at +m*1024 (so the kernel uses ONE pointer +16KB/step and
// 13-bit immediate offsets for m). frag f = ((L*8+kb)*4 + wv)*4 + m.
// lane (l16,q) of frag: Wt[ch = wv*64+m*16+l16][kb*32 + q*8 + 0..7] = W[k][ch]
__global__ void w_prep(const float* __restrict__ W2, const float* __restrict__ W3,
                       const float* __restrict__ W4, short* __restrict__ wlay) {
  int L = blockIdx.x >> 3, kb = blockIdx.x & 7;     // 24 blocks
  const float* W = (L == 0) ? W2 : (L == 1) ? W3 : W4;
  int m = threadIdx.x >> 6, lane = threadIdx.x & 63;
  int l16 = lane & 15, q = lane >> 4;
  for (int wv = 0; wv < 4; ++wv) {
    int ch = wv * 64 + m * 16 + l16;
    short8 pk;
    for (int i = 0; i < 8; ++i)
      pk[i] = (short)bfbits(W[(kb * 32 + q * 8 + i) * SZ + ch]);
    int f = ((L * 8 + kb) * 4 + wv) * 4 + m;
    reinterpret_cast<short8*>(wlay)[f * 64 + lane] = pk;
  }
}

// ---------------- main fused kernel ----------------
// One WG per (b, a, jhalf): 64 rows, 256 threads = 4 waves; wave tile 64ch x 64rows.
// 2-deep weight pipeline: awA/awB register banks; prefetch for step s+1 issues BEFORE
// step s's MFMA block (full ~300cyc cover). One wptr advanced +16KB/step, m-frags at
// immediate offsets. bfr split 2+2 keeps live regs low. No setprio (symmetric waves:
// T5 null/harmful). Demand ~155 regs -> 3 waves/SIMD at launch_bounds(,3).
__global__ __launch_bounds__(256, 3) void fused_mlp(
    const float* __restrict__ u, const float* __restrict__ v,
    const short* __restrict__ wlay,
    const float* __restrict__ b2, const float* __restrict__ b3, const float* __restrict__ b4,
    float* __restrict__ partial) {
  __shared__ __align__(16) short hbuf[64 * 256];   // 32 KB, byte ^= (row&7)<<4

  int wg = blockIdx.x;
  int b = wg >> 8, a = (wg >> 1) & 127, jh = wg & 1;
  int tid = threadIdx.x;
  int wave = tid >> 6, lane = tid & 63;
  int l16 = lane & 15, q = lane >> 4;

  const char* wptr = (const char*)wlay + wave * 4096 + lane * 16;  // step-0 chunk, per-lane

  short8 awA[4], awB[4];
  // preload step-0 fragments (latency hidden under h1 phase)
  #pragma unroll
  for (int m = 0; m < 4; ++m)
    awA[m] = *reinterpret_cast<const short8*>(wptr + m * 1024);

  // ---- h1 = relu(u[b,j] + v[b,a]) -> bf16, swizzled row-major in LDS ----
  {
    const float4* ub = (const float4*)(u + (size_t)b * NUMV * SZ) + jh * 64 * 64;
    const float4* vb = (const float4*)(v + ((size_t)b * NUMV + a) * SZ);
    #pragma unroll
    for (int it = 0; it < 16; ++it) {
      int flat = tid + it * 256;          // over 64 rows * 64 col-quads
      int jr = flat >> 6, c4 = flat & 63;
      float4 uu = ub[jr * 64 + c4];
      float4 vv = vb[c4];
      unsigned lo = (unsigned)bfbits(fmaxf(uu.x + vv.x, 0.f))
                  | ((unsigned)bfbits(fmaxf(uu.y + vv.y, 0.f)) << 16);
      unsigned hi = (unsigned)bfbits(fmaxf(uu.z + vv.z, 0.f))
                  | ((unsigned)bfbits(fmaxf(uu.w + vv.w, 0.f)) << 16);
      int byte = (jr * 512 + c4 * 8) ^ ((jr & 7) << 4);
      uint2 pk; pk.x = lo; pk.y = hi;
      *reinterpret_cast<uint2*>((char*)hbuf + byte) = pk;
    }
  }

  __syncthreads();        // h1 visible to all waves

  #pragma unroll
  for (int L = 0; L < 3; ++L) {
    const float* bb = (L == 0) ? b2 : (L == 1) ? b3 : b4;

    f32x4 acc[4][4];
    #pragma unroll
    for (int m = 0; m < 4; ++m)
      #pragma unroll
      for (int n = 0; n < 4; ++n)
        acc[m][n] = f32x4{0.f, 0.f, 0.f, 0.f};

    #pragma unroll
    for (int kb = 0; kb < 8; ++kb) {
      // prefetch step s+1 into the other bank, issued BEFORE this step's MFMAs.
      // linear layout: next chunk is always wptr+16KB (crosses layers seamlessly).
      if (L * 8 + kb < 23) {
        if ((kb & 1) == 0) {
          #pragma unroll
          for (int m = 0; m < 4; ++m)
            awB[m] = *reinterpret_cast<const short8*>(wptr + 16384 + m * 1024);
        } else {
          #pragma unroll
          for (int m = 0; m < 4; ++m)
            awA[m] = *reinterpret_cast<const short8*>(wptr + 16384 + m * 1024);
        }
      }
      wptr += 16384;

      // B-fragments in 2+2 split (keeps live regs low)
      short8 bfr0, bfr1, bfr2, bfr3;
      {
        int row0 = 0 * 16 + l16, row1 = 1 * 16 + l16;
        bfr0 = *reinterpret_cast<const short8*>((char*)hbuf +
               ((row0 * 512 + kb * 64 + q * 16) ^ ((row0 & 7) << 4)));
        bfr1 = *reinterpret_cast<const short8*>((char*)hbuf +
               ((row1 * 512 + kb * 64 + q * 16) ^ ((row1 & 7) << 4)));
      }
      if ((kb & 1) == 0) {
        #pragma unroll
        for (int m = 0; m < 4; ++m) {
          acc[m][0] = __builtin_amdgcn_mfma_f32_16x16x32_bf16(awA[m], bfr0, acc[m][0], 0, 0, 0);
          acc[m][1] = __builtin_amdgcn_mfma_f32_16x16x32_bf16(awA[m], bfr1, acc[m][1], 0, 0, 0);
        }
      } else {
        #pragma unroll
        for (int m = 0; m < 4; ++m) {
          acc[m][0] = __builtin_amdgcn_mfma_f32_16x16x32_bf16(awB[m], bfr0, acc[m][0], 0, 0, 0);
          acc[m][1] = __builtin_amdgcn_mfma_f32_16x16x32_bf16(awB[m], bfr1, acc[m][1], 0, 0, 0);
        }
      }
      {
        int row2 = 2 * 16 + l16, row3 = 3 * 16 + l16;
        bfr2 = *reinterpret_cast<const short8*>((char*)hbuf +
               ((row2 * 512 + kb * 64 + q * 16) ^ ((row2 & 7) << 4)));
        bfr3 = *reinterpret_cast<const short8*>((char*)hbuf +
               ((row3 * 512 + kb * 64 + q * 16) ^ ((row3 & 7) << 4)));
      }
      if ((kb & 1) == 0) {
        #pragma unroll
        for (int m = 0; m < 4; ++m) {
          acc[m][2] = __builtin_amdgcn_mfma_f32_16x16x32_bf16(awA[m], bfr2, acc[m][2], 0, 0, 0);
          acc[m][3] = __builtin_amdgcn_mfma_f32_16x16x32_bf16(awA[m], bfr3, acc[m][3], 0, 0, 0);
        }
      } else {
        #pragma unroll
        for (int m = 0; m < 4; ++m) {
          acc[m][2] = __builtin_amdgcn_mfma_f32_16x16x32_bf16(awB[m], bfr2, acc[m][2], 0, 0, 0);
          acc[m][3] = __builtin_amdgcn_mfma_f32_16x16x32_bf16(awB[m], bfr3, acc[m][3], 0, 0, 0);
        }
      }
    }

    __syncthreads();      // all waves done reading hbuf for this layer

    if (L < 2) {
      // epilogue: h_next[row][ch] = relu(acc+bias) -> swizzled hbuf, in place
      #pragma unroll
      for (int m = 0; m < 4; ++m) {
        f32x4 bv = *reinterpret_cast<const f32x4*>(bb + wave * 64 + m * 16 + q * 4);
        int ch = wave * 64 + m * 16 + q * 4;
        #pragma unroll
        for (int n = 0; n < 4; ++n) {
          int row = n * 16 + l16;
          f32x4 t = acc[m][n];
          unsigned lo = (unsigned)bfbits(fmaxf(t[0] + bv[0], 0.f))
                      | ((unsigned)bfbits(fmaxf(t[1] + bv[1], 0.f)) << 16);
          unsigned hi = (unsigned)bfbits(fmaxf(t[2] + bv[2], 0.f))
                      | ((unsigned)bfbits(fmaxf(t[3] + bv[3], 0.f)) << 16);
          int byte = (row * 512 + ch * 2) ^ ((row & 7) << 4);
          uint2 pk; pk.x = lo; pk.y = hi;
          *reinterpret_cast<uint2*>((char*)hbuf + byte) = pk;
        }
      }
      __syncthreads();    // h_next visible before next layer's reads
    } else {
      // final layer: relu+bias, sum this wave's 64 rows, write partial directly
      #pragma unroll
      for (int m = 0; m < 4; ++m) {
        f32x4 bv = *reinterpret_cast<const f32x4*>(bb + wave * 64 + m * 16 + q * 4);
        f32x4 s = f32x4{0.f, 0.f, 0.f, 0.f};
        #pragma unroll
        for (int n = 0; n < 4; ++n) {
          s[0] += fmaxf(acc[m][n][0] + bv[0], 0.f);
          s[1] += fmaxf(acc[m][n][1] + bv[1], 0.f);
          s[2] += fmaxf(acc[m][n][2] + bv[2], 0.f);
          s[3] += fmaxf(acc[m][n][3] + bv[3], 0.f);
        }
        #pragma unroll
        for (int r = 0; r < 4; ++r) {
          float x = s[r];
          x += __shfl_xor(x, 1);
          x += __shfl_xor(x, 2);
          x += __shfl_xor(x, 4);
          x += __shfl_xor(x, 8);
          s[r] = x;
        }
        if (l16 == 0) {
          float4 o; o.x = s[0]; o.y = s[1]; o.z = s[2]; o.w = s[3];
          *reinterpret_cast<float4*>(partial + (size_t)wg * SZ + wave * 64 + m * 16 + q * 4) = o;
        }
      }
    }
  }
}

// ---------------- final reduction over (a, jhalf): 256 slices per batch ----------------
__global__ void reduce_partials(const float* __restrict__ partial, float* __restrict__ out) {
  int b = blockIdx.x;            // 16 blocks x 256 threads
  int s = threadIdx.x;
  const float* p = partial + (size_t)b * 256 * SZ + s;
  float acc = 0.f;
  for (int i = 0; i < 256; ++i) acc += p[(size_t)i * SZ];
  out[b * SZ + s] = acc;
}

extern "C" void kernel_launch(void* const* d_in, const int* in_sizes, int n_in,
                              void* d_out, int out_size, void* d_ws, size_t ws_size,
                              hipStream_t stream) {
  const float* in_ = (const float*)d_in[0];
  const float* W1  = (const float*)d_in[1];
  const float* b1  = (const float*)d_in[2];
  const float* W2  = (const float*)d_in[3];
  const float* b2  = (const float*)d_in[4];
  const float* W3  = (const float*)d_in[5];
  const float* b3  = (const float*)d_in[6];
  const float* W4  = (const float*)d_in[7];
  const float* b4  = (const float*)d_in[8];
  float* out = (float*)d_out;

  char* ws = (char*)d_ws;
  float* u       = (float*)(ws);                                 // 2 MB
  float* v       = (float*)(ws + (2u << 20));                    // 2 MB
  short* wlay    = (short*)(ws + (4u << 20));                    // 384 KB
  float* partial = (float*)(ws + (4u << 20) + (1u << 19));       // 4 MB

  uv_prep<<<MBATCH * NUMV, 256, 0, stream>>>(in_, W1, b1, u, v);
  w_prep<<<24, 256, 0, stream>>>(W2, W3, W4, wlay);
  fused_mlp<<<MBATCH * NUMV * 2, 256, 0, stream>>>(u, v, wlay, b2, b3, b4, partial);
  reduce_partials<<<MBATCH, 256, 0, stream>>>(partial, out);
}